// Round 1
// baseline (179.740 us; speedup 1.0000x reference)
//
#include <hip/hip_runtime.h>
#include <math.h>

#define EPS_IN 1e-6f
#define EPS_IOU 1e-8f

__global__ __launch_bounds__(256) void rotated_iou_loss_kernel(
    const float* __restrict__ pred,
    const float* __restrict__ target,
    float* __restrict__ out,
    int n, float invN)
{
    int i = blockIdx.x * blockDim.x + threadIdx.x;
    float loss = 0.0f;
    if (i < n) {
        const float* P = pred + 7 * (size_t)i;
        const float* T = target + 7 * (size_t)i;
        float px = P[0], py = P[1], pz = P[2], pw = P[3], pl = P[4], ph = P[5], pa = P[6];
        float qx = T[0], qy = T[1], qz = T[2], qw = T[3], ql = T[4], qh = T[5], qa = T[6];

        // ---- corners (matches _box2corners) ----
        const float TXc[4] = {0.5f, -0.5f, -0.5f, 0.5f};
        const float TYc[4] = {0.5f, 0.5f, -0.5f, -0.5f};
        float c1x[4], c1y[4], c2x[4], c2y[4];
        float ca = cosf(pa), sa = sinf(pa);
        float cb = cosf(qa), sb = sinf(qa);
#pragma unroll
        for (int k = 0; k < 4; ++k) {
            float xx = TXc[k] * pw, yy = TYc[k] * pl;
            c1x[k] = xx * ca - yy * sa + px;
            c1y[k] = xx * sa + yy * ca + py;
            float x2 = TXc[k] * qw, y2 = TYc[k] * ql;
            c2x[k] = x2 * cb - y2 * sb + qx;
            c2y[k] = x2 * sb + y2 * cb + qy;
        }

        // ---- 24 candidate vertices: c1(0..3), c2(4..7), intersections(8..23) ----
        float vx[24], vy[24];
        unsigned mbits = 0;
#pragma unroll
        for (int k = 0; k < 4; ++k) { vx[k] = c1x[k]; vy[k] = c1y[k]; }
#pragma unroll
        for (int k = 0; k < 4; ++k) { vx[4 + k] = c2x[k]; vy[4 + k] = c2y[k]; }

        // c1 corners in box2
        {
            float ax = c2x[0], ay = c2y[0];
            float abx = c2x[1] - ax, aby = c2y[1] - ay;
            float adx = c2x[3] - ax, ady = c2y[3] - ay;
            float ab2 = abx * abx + aby * aby;
            float ad2 = adx * adx + ady * ady;
#pragma unroll
            for (int k = 0; k < 4; ++k) {
                float apx = c1x[k] - ax, apy = c1y[k] - ay;
                float pab = (apx * abx + apy * aby) / ab2;
                float pad = (apx * adx + apy * ady) / ad2;
                bool in = (pab > -EPS_IN) && (pab < 1.0f + EPS_IN) &&
                          (pad > -EPS_IN) && (pad < 1.0f + EPS_IN);
                if (in) mbits |= (1u << k);
            }
        }
        // c2 corners in box1
        {
            float ax = c1x[0], ay = c1y[0];
            float abx = c1x[1] - ax, aby = c1y[1] - ay;
            float adx = c1x[3] - ax, ady = c1y[3] - ay;
            float ab2 = abx * abx + aby * aby;
            float ad2 = adx * adx + ady * ady;
#pragma unroll
            for (int k = 0; k < 4; ++k) {
                float apx = c2x[k] - ax, apy = c2y[k] - ay;
                float pab = (apx * abx + apy * aby) / ab2;
                float pad = (apx * adx + apy * ady) / ad2;
                bool in = (pab > -EPS_IN) && (pab < 1.0f + EPS_IN) &&
                          (pad > -EPS_IN) && (pad < 1.0f + EPS_IN);
                if (in) mbits |= (1u << (4 + k));
            }
        }
        // edge intersections: index 8 + e1*4 + e2 (matches reshape(n,16))
#pragma unroll
        for (int e1 = 0; e1 < 4; ++e1) {
            float p1x = c1x[e1], p1y = c1y[e1];
            float p2x = c1x[(e1 + 1) & 3], p2y = c1y[(e1 + 1) & 3];
            float rx = p2x - p1x, ry = p2y - p1y;
#pragma unroll
            for (int e2 = 0; e2 < 4; ++e2) {
                float q1x = c2x[e2], q1y = c2y[e2];
                float q2x = c2x[(e2 + 1) & 3], q2y = c2y[(e2 + 1) & 3];
                float sx = q2x - q1x, sy = q2y - q1y;
                float den = rx * sy - ry * sx;
                float dsafe = (den == 0.0f) ? 1.0f : den;
                float qpx = q1x - p1x, qpy = q1y - p1y;
                float tt = (qpx * sy - qpy * sx) / dsafe;
                float uu = (qpx * ry - qpy * rx) / dsafe;
                bool mk = (den != 0.0f) && (tt > 0.0f) && (tt < 1.0f) &&
                          (uu > 0.0f) && (uu < 1.0f);
                int idx = 8 + e1 * 4 + e2;
                vx[idx] = mk ? (p1x + tt * rx) : 0.0f;
                vy[idx] = mk ? (p1y + tt * ry) : 0.0f;
                if (mk) mbits |= (1u << idx);
            }
        }

        // ---- polygon area (matches _polygon_area, argsort-by-angle shoelace) ----
        float nv = 0.0f, sx = 0.0f, sy = 0.0f;
#pragma unroll
        for (int k = 0; k < 24; ++k) {
            if ((mbits >> k) & 1u) { nv += 1.0f; sx += vx[k]; sy += vy[k]; }
        }
        nv = fmaxf(nv, 1.0f);
        float mx = sx / nv, my = sy / nv;

        float ang[24];
#pragma unroll
        for (int k = 0; k < 24; ++k) {
            vx[k] -= mx;
            vy[k] -= my;
            ang[k] = ((mbits >> k) & 1u) ? atan2f(vy[k], vx[k]) : 1e9f;
        }

        // v0 = vertex with min (angle, index) key (stable-argsort first element)
        float gAng = 1e30f;
        float gX = 0.0f, gY = 0.0f;
#pragma unroll
        for (int k = 0; k < 24; ++k) {
            if (ang[k] < gAng) { gAng = ang[k]; gX = vx[k]; gY = vy[k]; }
        }
        // unmasked slots hold v0 (reference: s = where(m, s, v0))
#pragma unroll
        for (int k = 0; k < 24; ++k) {
            if (!((mbits >> k) & 1u)) { vx[k] = gX; vy[k] = gY; }
        }

        // shoelace over angular successors; ties broken by original index
        // (exactly equal to sorted + roll(-1) sum in the reference)
        float area2 = 0.0f;
#pragma unroll
        for (int k = 0; k < 24; ++k) {
            float ak = ang[k];
            float bAng = 1e30f;
            int bIdx = 64;
            float bX = gX, bY = gY;  // wrap-around default: v0
#pragma unroll
            for (int j = 0; j < 24; ++j) {
                bool gtk = (ang[j] > ak) || (ang[j] == ak && j > k);
                bool ltb = (ang[j] < bAng) || (ang[j] == bAng && j < bIdx);
                if (gtk && ltb) { bAng = ang[j]; bIdx = j; bX = vx[j]; bY = vy[j]; }
            }
            area2 += vx[k] * bY - vy[k] * bX;
        }
        float inter_area = 0.5f * fabsf(area2);

        // ---- z overlap + IoU ----
        float zt = fminf(pz + 0.5f * ph, qz + 0.5f * qh);
        float zb = fmaxf(pz - 0.5f * ph, qz - 0.5f * qh);
        float hz = fmaxf(zt - zb, 0.0f);
        float inter_vol = inter_area * hz;
        float v1 = pw * pl * ph;
        float v2 = qw * ql * qh;
        float iou = inter_vol / (v1 + v2 - inter_vol + EPS_IOU);
        loss = (1.0f - iou) * invN;
    }

    // ---- reduction: wave shuffle -> LDS -> one atomic per block ----
#pragma unroll
    for (int off = 32; off > 0; off >>= 1)
        loss += __shfl_down(loss, off, 64);
    __shared__ float wsum[4];
    int lane = threadIdx.x & 63;
    int wid = threadIdx.x >> 6;
    if (lane == 0) wsum[wid] = loss;
    __syncthreads();
    if (threadIdx.x == 0) {
        atomicAdd(out, wsum[0] + wsum[1] + wsum[2] + wsum[3]);
    }
}

extern "C" void kernel_launch(void* const* d_in, const int* in_sizes, int n_in,
                              void* d_out, int out_size, void* d_ws, size_t ws_size,
                              hipStream_t stream) {
    const float* pred = (const float*)d_in[0];
    const float* target = (const float*)d_in[1];
    float* out = (float*)d_out;
    int n = in_sizes[0] / 7;

    hipMemsetAsync(d_out, 0, sizeof(float), stream);

    int block = 256;
    int grid = (n + block - 1) / block;
    rotated_iou_loss_kernel<<<grid, block, 0, stream>>>(pred, target, out, n,
                                                        1.0f / (float)n);
}

// Round 2
// 97.677 us; speedup vs baseline: 1.8401x; 1.8401x over previous
//
#include <hip/hip_runtime.h>
#include <math.h>

#define EPS_IOU 1e-8f

// Sum of  cross(a,b) over the portions of P's edges that lie inside convex
// CCW quad Q (Liang-Barsky segment clipping).  Summing this for P-edges-in-Q
// and Q-edges-in-P gives  2 * signed_area(P ∩ Q)  — order-independent, so no
// angular sort / atan2 needed.  Matches the reference area to ~1e-5 per item
// (mean over 500k ⇒ ~1e-6, threshold 1.14e-2).
__device__ __forceinline__ float clip_sum(const float px[4], const float py[4],
                                          const float qx[4], const float qy[4])
{
    // Q edge vectors (CCW; inside = left of edge: cross(e, p - q) >= 0)
    float ex[4], ey[4];
#pragma unroll
    for (int j = 0; j < 4; ++j) {
        ex[j] = qx[(j + 1) & 3] - qx[j];
        ey[j] = qy[(j + 1) & 3] - qy[j];
    }
    // signed distances of P's 4 vertices to Q's 4 edge lines
    float D[4][4];
#pragma unroll
    for (int i = 0; i < 4; ++i) {
#pragma unroll
        for (int j = 0; j < 4; ++j) {
            D[i][j] = ex[j] * (py[i] - qy[j]) - ey[j] * (px[i] - qx[j]);
        }
    }
    float s = 0.0f;
#pragma unroll
    for (int i = 0; i < 4; ++i) {
        const int i1 = (i + 1) & 3;
        float t0 = 0.0f, t1 = 1.0f;
#pragma unroll
        for (int j = 0; j < 4; ++j) {
            float d0 = D[i][j], d1 = D[i1][j];
            float den = d0 - d1;                       // >0: exiting, <0: entering
            float r = d0 * __builtin_amdgcn_rcpf(den); // ~1 ulp reciprocal
            if (den > 0.0f)      t1 = fminf(t1, r);
            else if (den < 0.0f) t0 = fmaxf(t0, r);
            else if (d0 < 0.0f)  t0 = 2.0f;            // edge fully outside plane
        }
        if (t0 < t1) {
            float dx = px[i1] - px[i], dy = py[i1] - py[i];
            float x0 = px[i] + t0 * dx, y0 = py[i] + t0 * dy;
            float x1 = px[i] + t1 * dx, y1 = py[i] + t1 * dy;
            s += x0 * y1 - y0 * x1;                    // ∫ x dy - y dx over segment
        }
    }
    return s;
}

__global__ __launch_bounds__(256) void rotated_iou_loss_kernel(
    const float* __restrict__ pred,
    const float* __restrict__ target,
    float* __restrict__ out,
    int n, float invN)
{
    int i = blockIdx.x * blockDim.x + threadIdx.x;
    float loss = 0.0f;
    if (i < n) {
        const float* P = pred + 7 * (size_t)i;
        const float* T = target + 7 * (size_t)i;
        float px = P[0], py = P[1], pz = P[2], pw = P[3], pl = P[4], ph = P[5], pa = P[6];
        float qx = T[0], qy = T[1], qz = T[2], qw = T[3], ql = T[4], qh = T[5], qa = T[6];

        // ---- corners (CCW, matches _box2corners) ----
        const float TXc[4] = {0.5f, -0.5f, -0.5f, 0.5f};
        const float TYc[4] = {0.5f, 0.5f, -0.5f, -0.5f};
        float ax[4], ay[4], bx[4], by[4];
        float ca, sa, cb, sb;
        __sincosf(pa, &sa, &ca);
        __sincosf(qa, &sb, &cb);
#pragma unroll
        for (int k = 0; k < 4; ++k) {
            float xx = TXc[k] * pw, yy = TYc[k] * pl;
            ax[k] = xx * ca - yy * sa + px;
            ay[k] = xx * sa + yy * ca + py;
            float x2 = TXc[k] * qw, y2 = TYc[k] * ql;
            bx[k] = x2 * cb - y2 * sb + qx;
            by[k] = x2 * sb + y2 * cb + qy;
        }

        // ---- intersection area: boundary-integral over clipped edges ----
        float s2 = clip_sum(ax, ay, bx, by) + clip_sum(bx, by, ax, ay);
        float inter_area = 0.5f * fabsf(s2);

        // ---- z overlap + IoU ----
        float zt = fminf(pz + 0.5f * ph, qz + 0.5f * qh);
        float zb = fmaxf(pz - 0.5f * ph, qz - 0.5f * qh);
        float hz = fmaxf(zt - zb, 0.0f);
        float inter_vol = inter_area * hz;
        float v1 = pw * pl * ph;
        float v2 = qw * ql * qh;
        float iou = inter_vol * __builtin_amdgcn_rcpf(v1 + v2 - inter_vol + EPS_IOU);
        loss = (1.0f - iou) * invN;
    }

    // ---- reduction: wave shuffle -> LDS -> one atomic per block ----
#pragma unroll
    for (int off = 32; off > 0; off >>= 1)
        loss += __shfl_down(loss, off, 64);
    __shared__ float wsum[4];
    int lane = threadIdx.x & 63;
    int wid = threadIdx.x >> 6;
    if (lane == 0) wsum[wid] = loss;
    __syncthreads();
    if (threadIdx.x == 0) {
        atomicAdd(out, wsum[0] + wsum[1] + wsum[2] + wsum[3]);
    }
}

extern "C" void kernel_launch(void* const* d_in, const int* in_sizes, int n_in,
                              void* d_out, int out_size, void* d_ws, size_t ws_size,
                              hipStream_t stream) {
    const float* pred = (const float*)d_in[0];
    const float* target = (const float*)d_in[1];
    float* out = (float*)d_out;
    int n = in_sizes[0] / 7;

    hipMemsetAsync(d_out, 0, sizeof(float), stream);

    int block = 256;
    int grid = (n + block - 1) / block;
    rotated_iou_loss_kernel<<<grid, block, 0, stream>>>(pred, target, out, n,
                                                        1.0f / (float)n);
}

// Round 3
// 85.058 us; speedup vs baseline: 2.1131x; 1.1484x over previous
//
#include <hip/hip_runtime.h>
#include <math.h>

#define EPS_IOU 1e-8f
#define IPB 512              // items per block (2 per thread)
#define NF (IPB * 7)         // floats per input array per block

// Sum of cross(a,b) over the portions of P's edges inside convex CCW quad Q
// (Liang-Barsky).  clip_sum(P,Q)+clip_sum(Q,P) = 2*signed_area(P∩Q) —
// order-independent boundary integral, no sort/atan2. Fully branchless.
__device__ __forceinline__ float clip_sum(const float px[4], const float py[4],
                                          const float qx[4], const float qy[4])
{
    float ex[4], ey[4];
#pragma unroll
    for (int j = 0; j < 4; ++j) {
        ex[j] = qx[(j + 1) & 3] - qx[j];
        ey[j] = qy[(j + 1) & 3] - qy[j];
    }
    float D[4][4];
#pragma unroll
    for (int i = 0; i < 4; ++i) {
#pragma unroll
        for (int j = 0; j < 4; ++j) {
            D[i][j] = ex[j] * (py[i] - qy[j]) - ey[j] * (px[i] - qx[j]);
        }
    }
    float s = 0.0f;
#pragma unroll
    for (int i = 0; i < 4; ++i) {
        const int i1 = (i + 1) & 3;
        float t0 = 0.0f, t1 = 1.0f;
#pragma unroll
        for (int j = 0; j < 4; ++j) {
            float d0 = D[i][j], d1 = D[i1][j];
            float den = d0 - d1;
            float r = d0 * __builtin_amdgcn_rcpf(den);
            t1 = (den > 0.0f) ? fminf(t1, r) : t1;                  // exiting
            t0 = (den < 0.0f) ? fmaxf(t0, r) : t0;                  // entering
            t0 = (den == 0.0f && d0 < 0.0f) ? 2.0f : t0;            // fully out
        }
        float dx = px[i1] - px[i], dy = py[i1] - py[i];
        float x0 = px[i] + t0 * dx, y0 = py[i] + t0 * dy;
        float x1 = px[i] + t1 * dx, y1 = py[i] + t1 * dy;
        float cr = x0 * y1 - y0 * x1;
        s += (t0 < t1) ? cr : 0.0f;
    }
    return s;
}

__device__ __forceinline__ float one_loss(const float* __restrict__ P,
                                          const float* __restrict__ T)
{
    float px = P[0], py = P[1], pz = P[2], pw = P[3], pl = P[4], ph = P[5], pa = P[6];
    float qx = T[0], qy = T[1], qz = T[2], qw = T[3], ql = T[4], qh = T[5], qa = T[6];

    const float TXc[4] = {0.5f, -0.5f, -0.5f, 0.5f};
    const float TYc[4] = {0.5f, 0.5f, -0.5f, -0.5f};
    float ax[4], ay[4], bx[4], by[4];
    float ca, sa, cb, sb;
    __sincosf(pa, &sa, &ca);
    __sincosf(qa, &sb, &cb);
#pragma unroll
    for (int k = 0; k < 4; ++k) {
        float xx = TXc[k] * pw, yy = TYc[k] * pl;
        ax[k] = xx * ca - yy * sa + px;
        ay[k] = xx * sa + yy * ca + py;
        float x2 = TXc[k] * qw, y2 = TYc[k] * ql;
        bx[k] = x2 * cb - y2 * sb + qx;
        by[k] = x2 * sb + y2 * cb + qy;
    }

    float s2 = clip_sum(ax, ay, bx, by) + clip_sum(bx, by, ax, ay);
    float inter_area = 0.5f * fabsf(s2);

    float zt = fminf(pz + 0.5f * ph, qz + 0.5f * qh);
    float zb = fmaxf(pz - 0.5f * ph, qz - 0.5f * qh);
    float hz = fmaxf(zt - zb, 0.0f);
    float inter_vol = inter_area * hz;
    float v1 = pw * pl * ph;
    float v2 = qw * ql * qh;
    float iou = inter_vol * __builtin_amdgcn_rcpf(v1 + v2 - inter_vol + EPS_IOU);
    return 1.0f - iou;
}

__global__ __launch_bounds__(256) void iou_main_kernel(
    const float* __restrict__ pred,
    const float* __restrict__ target,
    float* __restrict__ partial,
    int n, float invN)
{
    __shared__ float sP[NF];
    __shared__ float sT[NF];

    const int base = blockIdx.x * IPB;
    const int rem = min(IPB, n - base);     // items this block handles
    const int nf = rem * 7;                 // floats per array this block

    // coalesced float4 staging (base*7 is a multiple of 3584 -> 16B aligned)
    const float4* gp = (const float4*)(pred + (size_t)base * 7);
    const float4* gt = (const float4*)(target + (size_t)base * 7);
    float4* lp = (float4*)sP;
    float4* lt = (float4*)sT;
    for (int k = threadIdx.x; k * 4 < nf; k += 256) {
        if (k * 4 + 3 < nf) {
            lp[k] = gp[k];
            lt[k] = gt[k];
        } else {
            for (int c = k * 4; c < nf; ++c) {
                sP[c] = pred[(size_t)base * 7 + c];
                sT[c] = target[(size_t)base * 7 + c];
            }
        }
    }
    __syncthreads();

    float loss = 0.0f;
#pragma unroll
    for (int it = 0; it < 2; ++it) {
        int j = threadIdx.x + it * 256;
        if (j < rem) loss += one_loss(sP + 7 * j, sT + 7 * j) * invN;
    }

    // wave shuffle -> LDS -> per-block partial (no atomics)
#pragma unroll
    for (int off = 32; off > 0; off >>= 1)
        loss += __shfl_down(loss, off, 64);
    __shared__ float wsum[4];
    int lane = threadIdx.x & 63;
    int wid = threadIdx.x >> 6;
    if (lane == 0) wsum[wid] = loss;
    __syncthreads();
    if (threadIdx.x == 0)
        partial[blockIdx.x] = wsum[0] + wsum[1] + wsum[2] + wsum[3];
}

__global__ __launch_bounds__(256) void iou_reduce_kernel(
    const float* __restrict__ partial, float* __restrict__ out, int g)
{
    float s = 0.0f;
    for (int k = threadIdx.x; k < g; k += 256) s += partial[k];
#pragma unroll
    for (int off = 32; off > 0; off >>= 1)
        s += __shfl_down(s, off, 64);
    __shared__ float wsum[4];
    int lane = threadIdx.x & 63;
    int wid = threadIdx.x >> 6;
    if (lane == 0) wsum[wid] = s;
    __syncthreads();
    if (threadIdx.x == 0)
        out[0] = wsum[0] + wsum[1] + wsum[2] + wsum[3];
}

extern "C" void kernel_launch(void* const* d_in, const int* in_sizes, int n_in,
                              void* d_out, int out_size, void* d_ws, size_t ws_size,
                              hipStream_t stream) {
    const float* pred = (const float*)d_in[0];
    const float* target = (const float*)d_in[1];
    float* out = (float*)d_out;
    float* partial = (float*)d_ws;
    int n = in_sizes[0] / 7;

    int grid = (n + IPB - 1) / IPB;
    iou_main_kernel<<<grid, 256, 0, stream>>>(pred, target, partial, n,
                                              1.0f / (float)n);
    iou_reduce_kernel<<<1, 256, 0, stream>>>(partial, out, grid);
}

// Round 4
// 76.463 us; speedup vs baseline: 2.3507x; 1.1124x over previous
//
#include <hip/hip_runtime.h>
#include <math.h>

#define EPS_IOU 1e-8f
#define IPB 512              // items per block (2 per thread)
#define NF (IPB * 7)         // floats per input array per block

// Branch-free slab clip: fraction of segment s + t*d, t in [0,1], inside the
// axis-aligned box [-hx,hx]x[-hy,hy].  rdx/rdy are reciprocals of d.
// Parallel-edge (d component == 0) cases resolve via +-inf through min/max;
// NaN (measure-zero: start exactly on a slab plane with parallel dir) is
// absorbed by IEEE minNum/maxNum and by the final fmaxf(.,0).
__device__ __forceinline__ float slab_dt(float sx, float sy,
                                         float rdx, float rdy,
                                         float hx, float hy)
{
    float tx1 = (-hx - sx) * rdx, tx2 = (hx - sx) * rdx;
    float ty1 = (-hy - sy) * rdy, ty2 = (hy - sy) * rdy;
    float t0 = fmaxf(fmaxf(fminf(tx1, tx2), fminf(ty1, ty2)), 0.0f); // v_max3
    float t1 = fminf(fminf(fmaxf(tx1, tx2), fmaxf(ty1, ty2)), 1.0f); // v_min3
    return fmaxf(t1 - t0, 0.0f);
}

__device__ __forceinline__ float one_loss(const float* __restrict__ P,
                                          const float* __restrict__ T)
{
    float px = P[0], py = P[1], pz = P[2], pw = P[3], pl = P[4], ph = P[5], pa = P[6];
    float qx = T[0], qy = T[1], qz = T[2], qw = T[3], ql = T[4], qh = T[5], qa = T[6];

    float hpx = 0.5f * pw, hpy = 0.5f * pl;
    float hqx = 0.5f * qw, hqy = 0.5f * ql;

    float ca, sa, cb, sb;
    __sincosf(pa, &sa, &ca);
    __sincosf(qa, &sb, &cb);
    float ct = ca * cb + sa * sb;     // cos(qa - pa)
    float st = sb * ca - sa * cb;     // sin(qa - pa)

    // Q center in P's frame
    float dxw = qx - px, dyw = qy - py;
    float cx_ =  ca * dxw + sa * dyw;
    float cy_ = -sa * dxw + ca * dyw;

    // Q half-axes in P frame: u = R(th)*(hqx,0), v = R(th)*(0,hqy)
    float ux = ct * hqx, uy = st * hqx;
    float vx = -st * hqy, vy = ct * hqy;

    // reciprocals of Q edge dirs (+-2u, +-2v): 4 rcps, sign-flip reuse
    float r2ux = __builtin_amdgcn_rcpf(2.0f * ux);
    float r2uy = __builtin_amdgcn_rcpf(2.0f * uy);
    float r2vx = __builtin_amdgcn_rcpf(2.0f * vx);
    float r2vy = __builtin_amdgcn_rcpf(2.0f * vy);

    // Q corners in P frame (CCW, matches ref corner order)
    float upx = ux + vx, upy = uy + vy;   // u+v
    float umx = ux - vx, umy = uy - vy;   // u-v
    // e0: s=c+u+v d=-2u | e1: s=c-u+v d=-2v | e2: s=c-u-v d=+2u | e3: s=c+u-v d=+2v
    float dq0 = slab_dt(cx_ + upx, cy_ + upy, -r2ux, -r2uy, hpx, hpy);
    float dq1 = slab_dt(cx_ - umx, cy_ - umy, -r2vx, -r2vy, hpx, hpy);
    float dq2 = slab_dt(cx_ - upx, cy_ - upy,  r2ux,  r2uy, hpx, hpy);
    float dq3 = slab_dt(cx_ + umx, cy_ + umy,  r2vx,  r2vy, hpx, hpy);

    // cross(s_i, d_i) for Q edges: +-2Cu/+-2Cv + 2W  (W = cross(u,v) = hqx*hqy)
    float Cu = cx_ * uy - cy_ * ux;
    float Cv = cx_ * vy - cy_ * vx;
    float W2 = 2.0f * (hqx * hqy);
    float Cu2 = 2.0f * Cu, Cv2 = 2.0f * Cv;
    float area2 = dq0 * (W2 - Cu2) + dq1 * (W2 - Cv2)
                + dq2 * (W2 + Cu2) + dq3 * (W2 + Cv2);

    // P edges clipped against Q, computed in Q's frame (t is affine-invariant;
    // every P edge has cross(s,d) = 2*hpx*hpy in P's frame)
    float u2x = ct * hpx, u2y = -st * hpx;   // R(-th)*(hpx,0)
    float v2x = st * hpy, v2y = ct * hpy;    // R(-th)*(0,hpy)
    float c2x = -(ct * cx_ + st * cy_);      // P center in Q frame
    float c2y = st * cx_ - ct * cy_;

    float r2u2x = __builtin_amdgcn_rcpf(2.0f * u2x);
    float r2u2y = __builtin_amdgcn_rcpf(2.0f * u2y);
    float r2v2x = __builtin_amdgcn_rcpf(2.0f * v2x);
    float r2v2y = __builtin_amdgcn_rcpf(2.0f * v2y);

    float up2x = u2x + v2x, up2y = u2y + v2y;
    float um2x = u2x - v2x, um2y = u2y - v2y;
    float dtp = slab_dt(c2x + up2x, c2y + up2y, -r2u2x, -r2u2y, hqx, hqy)
              + slab_dt(c2x - um2x, c2y - um2y, -r2v2x, -r2v2y, hqx, hqy)
              + slab_dt(c2x - up2x, c2y - up2y,  r2u2x,  r2u2y, hqx, hqy)
              + slab_dt(c2x + um2x, c2y + um2y,  r2v2x,  r2v2y, hqx, hqy);
    area2 += dtp * (2.0f * (hpx * hpy));

    float inter_area = 0.5f * fabsf(area2);

    // ---- z overlap + IoU ----
    float zt = fminf(pz + 0.5f * ph, qz + 0.5f * qh);
    float zb = fmaxf(pz - 0.5f * ph, qz - 0.5f * qh);
    float hz = fmaxf(zt - zb, 0.0f);
    float inter_vol = inter_area * hz;
    float v1 = pw * pl * ph;
    float v2 = qw * ql * qh;
    float iou = inter_vol * __builtin_amdgcn_rcpf(v1 + v2 - inter_vol + EPS_IOU);
    return 1.0f - iou;
}

__global__ __launch_bounds__(256) void iou_main_kernel(
    const float* __restrict__ pred,
    const float* __restrict__ target,
    float* __restrict__ partial,
    int n, float invN)
{
    __shared__ float sP[NF];
    __shared__ float sT[NF];

    const int base = blockIdx.x * IPB;
    const int rem = min(IPB, n - base);
    const int nf = rem * 7;

    // coalesced float4 staging (base*7*4B is a multiple of 14336 -> aligned)
    const float4* gp = (const float4*)(pred + (size_t)base * 7);
    const float4* gt = (const float4*)(target + (size_t)base * 7);
    float4* lp = (float4*)sP;
    float4* lt = (float4*)sT;
    for (int k = threadIdx.x; k * 4 < nf; k += 256) {
        if (k * 4 + 3 < nf) {
            lp[k] = gp[k];
            lt[k] = gt[k];
        } else {
            for (int c = k * 4; c < nf; ++c) {
                sP[c] = pred[(size_t)base * 7 + c];
                sT[c] = target[(size_t)base * 7 + c];
            }
        }
    }
    __syncthreads();

    float loss = 0.0f;
#pragma unroll
    for (int it = 0; it < 2; ++it) {
        int j = threadIdx.x + it * 256;
        if (j < rem) loss += one_loss(sP + 7 * j, sT + 7 * j) * invN;
    }

#pragma unroll
    for (int off = 32; off > 0; off >>= 1)
        loss += __shfl_down(loss, off, 64);
    __shared__ float wsum[4];
    int lane = threadIdx.x & 63;
    int wid = threadIdx.x >> 6;
    if (lane == 0) wsum[wid] = loss;
    __syncthreads();
    if (threadIdx.x == 0)
        partial[blockIdx.x] = wsum[0] + wsum[1] + wsum[2] + wsum[3];
}

__global__ __launch_bounds__(256) void iou_reduce_kernel(
    const float* __restrict__ partial, float* __restrict__ out, int g)
{
    float s = 0.0f;
    for (int k = threadIdx.x; k < g; k += 256) s += partial[k];
#pragma unroll
    for (int off = 32; off > 0; off >>= 1)
        s += __shfl_down(s, off, 64);
    __shared__ float wsum[4];
    int lane = threadIdx.x & 63;
    int wid = threadIdx.x >> 6;
    if (lane == 0) wsum[wid] = s;
    __syncthreads();
    if (threadIdx.x == 0)
        out[0] = wsum[0] + wsum[1] + wsum[2] + wsum[3];
}

extern "C" void kernel_launch(void* const* d_in, const int* in_sizes, int n_in,
                              void* d_out, int out_size, void* d_ws, size_t ws_size,
                              hipStream_t stream) {
    const float* pred = (const float*)d_in[0];
    const float* target = (const float*)d_in[1];
    float* out = (float*)d_out;
    float* partial = (float*)d_ws;
    int n = in_sizes[0] / 7;

    int grid = (n + IPB - 1) / IPB;
    iou_main_kernel<<<grid, 256, 0, stream>>>(pred, target, partial, n,
                                              1.0f / (float)n);
    iou_reduce_kernel<<<1, 256, 0, stream>>>(partial, out, grid);
}

// Round 5
// 75.414 us; speedup vs baseline: 2.3834x; 1.0139x over previous
//
#include <hip/hip_runtime.h>
#include <math.h>

#define EPS_IOU 1e-8f

// Branch-free slab clip with HALF-length direction d (t in [0,2]):
// fraction-of-parameter of segment s + t*d inside [-hx,hx]x[-hy,hy].
// rdx/rdy are reciprocals of the half-direction components.  Parallel-edge
// cases resolve via +-inf through min/max; NaN (measure-zero) absorbed by
// IEEE minNum/maxNum + final clamp.
__device__ __forceinline__ float slab_dt(float sx, float sy,
                                         float rdx, float rdy,
                                         float hx, float hy)
{
    float tx1 = (-hx - sx) * rdx, tx2 = (hx - sx) * rdx;
    float ty1 = (-hy - sy) * rdy, ty2 = (hy - sy) * rdy;
    float t0 = fmaxf(fmaxf(fminf(tx1, tx2), fminf(ty1, ty2)), 0.0f); // v_max3
    float t1 = fminf(fminf(fmaxf(tx1, tx2), fmaxf(ty1, ty2)), 2.0f); // v_min3
    return fmaxf(t1 - t0, 0.0f);
}

// Boundary-integral rotated-rect intersection:
//   2*Area(P∩Q) = Σ_over_clipped_edges Δt · cross(s, d)
// computed per-box-frame so every clip is an axis-aligned slab test and every
// cross(s,d) has a closed form.  Order-independent: no sort / atan2.
__device__ __forceinline__ float one_loss(float px, float py, float pz,
                                          float pw, float pl, float ph, float pa,
                                          float qx, float qy, float qz,
                                          float qw, float ql, float qh, float qa)
{
    float hpx = 0.5f * pw, hpy = 0.5f * pl;
    float hqx = 0.5f * qw, hqy = 0.5f * ql;

    float sa = __sinf(pa), ca = __cosf(pa);
    float sb = __sinf(qa), cb = __cosf(qa);
    float ct = ca * cb + sa * sb;     // cos(qa - pa)
    float st = sb * ca - sa * cb;     // sin(qa - pa)

    // Q center in P's frame
    float dxw = qx - px, dyw = qy - py;
    float cx_ =  ca * dxw + sa * dyw;
    float cy_ = -sa * dxw + ca * dyw;

    // Q half-axes in P frame
    float ux = ct * hqx, uy = st * hqx;
    float vx = -st * hqy, vy = ct * hqy;

    float rux = __builtin_amdgcn_rcpf(ux);
    float ruy = __builtin_amdgcn_rcpf(uy);
    float rvx = __builtin_amdgcn_rcpf(vx);
    float rvy = __builtin_amdgcn_rcpf(vy);

    // Q corners in P frame (CCW): e0 s=c+u+v d=-u | e1 s=c-u+v d=-v |
    //                             e2 s=c-u-v d=+u | e3 s=c+u-v d=+v
    float upx = ux + vx, upy = uy + vy;
    float umx = ux - vx, umy = uy - vy;
    float dq0 = slab_dt(cx_ + upx, cy_ + upy, -rux, -ruy, hpx, hpy);
    float dq1 = slab_dt(cx_ - umx, cy_ - umy, -rvx, -rvy, hpx, hpy);
    float dq2 = slab_dt(cx_ - upx, cy_ - upy,  rux,  ruy, hpx, hpy);
    float dq3 = slab_dt(cx_ + umx, cy_ + umy,  rvx,  rvy, hpx, hpy);

    // cross(s,d) per edge: W∓Cu / W∓Cv  (W = cross(u,v) = hqx*hqy)
    float Cu = cx_ * uy - cy_ * ux;
    float Cv = cx_ * vy - cy_ * vx;
    float W = hqx * hqy;
    float area2 = dq0 * (W - Cu) + dq1 * (W - Cv)
                + dq2 * (W + Cu) + dq3 * (W + Cv);

    // P edges clipped in Q's frame (t affine-invariant); each P edge has
    // cross(s, half-d) = hpx*hpy in P's frame.
    float u2x = ct * hpx, u2y = -st * hpx;
    float v2x = st * hpy, v2y = ct * hpy;
    float c2x = -(ct * cx_ + st * cy_);
    float c2y = st * cx_ - ct * cy_;

    float ru2x = __builtin_amdgcn_rcpf(u2x);
    float ru2y = __builtin_amdgcn_rcpf(u2y);
    float rv2x = __builtin_amdgcn_rcpf(v2x);
    float rv2y = __builtin_amdgcn_rcpf(v2y);

    float up2x = u2x + v2x, up2y = u2y + v2y;
    float um2x = u2x - v2x, um2y = u2y - v2y;
    float dtp = slab_dt(c2x + up2x, c2y + up2y, -ru2x, -ru2y, hqx, hqy)
              + slab_dt(c2x - um2x, c2y - um2y, -rv2x, -rv2y, hqx, hqy)
              + slab_dt(c2x - up2x, c2y - up2y,  ru2x,  ru2y, hqx, hqy)
              + slab_dt(c2x + um2x, c2y + um2y,  rv2x,  rv2y, hqx, hqy);
    area2 += dtp * (hpx * hpy);

    float inter_area = 0.5f * fabsf(area2);

    float zt = fminf(pz + 0.5f * ph, qz + 0.5f * qh);
    float zb = fmaxf(pz - 0.5f * ph, qz - 0.5f * qh);
    float hz = fmaxf(zt - zb, 0.0f);
    float inter_vol = inter_area * hz;
    float v1 = pw * pl * ph;
    float v2 = qw * ql * qh;
    float iou = inter_vol * __builtin_amdgcn_rcpf(v1 + v2 - inter_vol + EPS_IOU);
    return 1.0f - iou;
}

__global__ __launch_bounds__(256) void iou_main_kernel(
    const float* __restrict__ pred,
    const float* __restrict__ target,
    float* __restrict__ partial,
    int n)
{
    int i = blockIdx.x * 256 + threadIdx.x;
    float loss = 0.0f;
    if (i < n) {
        const float* P = pred + 7 * (size_t)i;
        const float* T = target + 7 * (size_t)i;
        loss = one_loss(P[0], P[1], P[2], P[3], P[4], P[5], P[6],
                        T[0], T[1], T[2], T[3], T[4], T[5], T[6]);
    }

    // wave shuffle -> LDS -> uncontended per-block partial
#pragma unroll
    for (int off = 32; off > 0; off >>= 1)
        loss += __shfl_down(loss, off, 64);
    __shared__ float wsum[4];
    int lane = threadIdx.x & 63;
    int wid = threadIdx.x >> 6;
    if (lane == 0) wsum[wid] = loss;
    __syncthreads();
    if (threadIdx.x == 0)
        partial[blockIdx.x] = wsum[0] + wsum[1] + wsum[2] + wsum[3];
}

__global__ __launch_bounds__(256) void iou_reduce_kernel(
    const float* __restrict__ partial, float* __restrict__ out,
    int g, float invN)
{
    float s = 0.0f;
    for (int k = threadIdx.x; k < g; k += 256) s += partial[k];
#pragma unroll
    for (int off = 32; off > 0; off >>= 1)
        s += __shfl_down(s, off, 64);
    __shared__ float wsum[4];
    int lane = threadIdx.x & 63;
    int wid = threadIdx.x >> 6;
    if (lane == 0) wsum[wid] = s;
    __syncthreads();
    if (threadIdx.x == 0)
        out[0] = (wsum[0] + wsum[1] + wsum[2] + wsum[3]) * invN;
}

extern "C" void kernel_launch(void* const* d_in, const int* in_sizes, int n_in,
                              void* d_out, int out_size, void* d_ws, size_t ws_size,
                              hipStream_t stream) {
    const float* pred = (const float*)d_in[0];
    const float* target = (const float*)d_in[1];
    float* out = (float*)d_out;
    float* partial = (float*)d_ws;
    int n = in_sizes[0] / 7;

    int grid = (n + 255) / 256;
    iou_main_kernel<<<grid, 256, 0, stream>>>(pred, target, partial, n);
    iou_reduce_kernel<<<1, 256, 0, stream>>>(partial, out, grid, 1.0f / (float)n);
}